// Round 1
// baseline (593.341 us; speedup 1.0000x reference)
//
#include <hip/hip_runtime.h>

#define N_FEAT 128
#define F1 16
#define F2 2

// ---------------- degree ----------------
__global__ void deg_kernel(const int* __restrict__ col, int E, int* __restrict__ deg) {
    int i = blockIdx.x * blockDim.x + threadIdx.x;
    if (i < E) atomicAdd(&deg[col[i]], 1);
}

__global__ void dinv_kernel(const int* __restrict__ deg, float* __restrict__ dinv, int N) {
    int i = blockIdx.x * blockDim.x + threadIdx.x;
    if (i < N) dinv[i] = rsqrtf((float)(deg[i] + 1));  // +1 self loop
}

// ---------------- layer-1 GEMM: hs[r,f] = dinv[r] * sum_k x[r,k]*W1[k,f] ----------------
__global__ __launch_bounds__(256) void gemm1_kernel(
    const float* __restrict__ x, const float* __restrict__ W1,
    const float* __restrict__ dinv, float* __restrict__ hs, int N) {
    __shared__ float ws[N_FEAT * F1];   // W1 [k][f], 2048 floats
    __shared__ float xs[16][N_FEAT];    // 16 rows of x
    int t = threadIdx.x;
    for (int i = t; i < N_FEAT * F1; i += 256) ws[i] = W1[i];
    int row0 = blockIdx.x * 16;
    for (int i = t; i < 16 * N_FEAT; i += 256) {
        int r = i >> 7, k = i & 127;
        int row = row0 + r;
        xs[r][k] = (row < N) ? x[row * N_FEAT + k] : 0.f;
    }
    __syncthreads();
    int rr = t >> 4, f = t & 15;
    int row = row0 + rr;
    if (row < N) {
        float acc = 0.f;
#pragma unroll
        for (int k = 0; k < N_FEAT; ++k) acc += xs[rr][k] * ws[k * F1 + f];
        hs[row * F1 + f] = acc * dinv[row];
    }
}

// ---------------- scatter layer 1: acc[c,f] += hs[r,f] ----------------
__global__ void scatter1_kernel(const int* __restrict__ rowi, const int* __restrict__ coli,
                                const float* __restrict__ hs, float* __restrict__ acc,
                                long long total) {
    long long gid = (long long)blockIdx.x * blockDim.x + threadIdx.x;
    if (gid >= total) return;
    int e = (int)(gid >> 4);
    int f = (int)(gid & 15);
    int r = rowi[e], c = coli[e];
    atomicAdd(&acc[c * F1 + f], hs[r * F1 + f]);
}

// ---------------- finalize layer 1 + relu + GEMM2: hs2[i,j] = dinv[i]*sum_f relu(...)*W2[f,j] --
__global__ __launch_bounds__(256) void layer2_kernel(
    const float* __restrict__ acc, const float* __restrict__ hs,
    const float* __restrict__ dinv, const float* __restrict__ b1,
    const float* __restrict__ W2, float* __restrict__ hs2, int N) {
    __shared__ float w2s[F1 * F2];
    __shared__ float b1s[F1];
    int t = threadIdx.x;
    if (t < F1 * F2) w2s[t] = W2[t];
    if (t < F1) b1s[t] = b1[t];
    __syncthreads();
    int i = blockIdx.x * blockDim.x + t;
    if (i >= N) return;
    float di = dinv[i];
    const float4* a4 = (const float4*)(acc + (size_t)i * F1);
    const float4* s4 = (const float4*)(hs + (size_t)i * F1);
    float h0 = 0.f, h1 = 0.f;
#pragma unroll
    for (int q = 0; q < 4; ++q) {
        float4 a = a4[q], s = s4[q];
        float v[4] = {a.x + s.x, a.y + s.y, a.z + s.z, a.w + s.w};
#pragma unroll
        for (int u = 0; u < 4; ++u) {
            int f = q * 4 + u;
            float o = fmaxf(di * v[u] + b1s[f], 0.f);
            h0 += o * w2s[f * F2 + 0];
            h1 += o * w2s[f * F2 + 1];
        }
    }
    hs2[(size_t)i * F2 + 0] = h0 * di;
    hs2[(size_t)i * F2 + 1] = h1 * di;
}

// ---------------- scatter layer 2: out[c,j] += hs2[r,j] ----------------
__global__ void scatter2_kernel(const int* __restrict__ rowi, const int* __restrict__ coli,
                                const float* __restrict__ hs2, float* __restrict__ out,
                                long long total) {
    long long gid = (long long)blockIdx.x * blockDim.x + threadIdx.x;
    if (gid >= total) return;
    int e = (int)(gid >> 1);
    int j = (int)(gid & 1);
    atomicAdd(&out[coli[e] * F2 + j], hs2[rowi[e] * F2 + j]);
}

// ---------------- finalize layer 2 ----------------
__global__ void fin2_kernel(float* __restrict__ out, const float* __restrict__ hs2,
                            const float* __restrict__ dinv, const float* __restrict__ b2, int N) {
    int gid = blockIdx.x * blockDim.x + threadIdx.x;
    if (gid >= N * F2) return;
    int i = gid >> 1, j = gid & 1;
    out[gid] = dinv[i] * (out[gid] + hs2[gid]) + b2[j];
}

extern "C" void kernel_launch(void* const* d_in, const int* in_sizes, int n_in,
                              void* d_out, int out_size, void* d_ws, size_t ws_size,
                              hipStream_t stream) {
    const float* x  = (const float*)d_in[0];
    const int*   ei = (const int*)d_in[1];
    const float* W1 = (const float*)d_in[2];
    const float* b1 = (const float*)d_in[3];
    const float* W2 = (const float*)d_in[4];
    const float* b2 = (const float*)d_in[5];
    int N = in_sizes[0] / N_FEAT;
    int E = in_sizes[1] / 2;
    const int* rowi = ei;        // edge_index[0] = src
    const int* coli = ei + E;    // edge_index[1] = dst
    float* out = (float*)d_out;

    // workspace layout (floats), regions padded to 1024-float alignment
    size_t NP = ((size_t)N + 1023) & ~(size_t)1023;
    float* wsf  = (float*)d_ws;
    int*   deg  = (int*)wsf;             // NP ints
    float* dinv = wsf + NP;              // NP
    float* hs   = wsf + 2 * NP;          // 16*NP
    float* acc  = wsf + 18 * NP;         // 16*NP
    float* hs2  = wsf + 34 * NP;         // 2*NP

    hipMemsetAsync(deg, 0, (size_t)N * sizeof(int), stream);
    hipMemsetAsync(acc, 0, (size_t)N * F1 * sizeof(float), stream);
    hipMemsetAsync(out, 0, (size_t)N * F2 * sizeof(float), stream);

    deg_kernel<<<(E + 255) / 256, 256, 0, stream>>>(coli, E, deg);
    dinv_kernel<<<(N + 255) / 256, 256, 0, stream>>>(deg, dinv, N);
    gemm1_kernel<<<(N + 15) / 16, 256, 0, stream>>>(x, W1, dinv, hs, N);

    long long tot1 = (long long)E * F1;
    scatter1_kernel<<<(int)((tot1 + 255) / 256), 256, 0, stream>>>(rowi, coli, hs, acc, tot1);

    layer2_kernel<<<(N + 255) / 256, 256, 0, stream>>>(acc, hs, dinv, b1, W2, hs2, N);

    long long tot2 = (long long)E * F2;
    scatter2_kernel<<<(int)((tot2 + 255) / 256), 256, 0, stream>>>(rowi, coli, hs2, out, tot2);

    fin2_kernel<<<(N * F2 + 255) / 256, 256, 0, stream>>>(out, hs2, dinv, b2, N);
}